// Round 3
// baseline (233.758 us; speedup 1.0000x reference)
//
#include <hip/hip_runtime.h>
#include <hip/hip_bf16.h>
#include <stdint.h>

#define DOUT 1024
#define NMAX 16384

#define BM 256
#define BN 128
#define LDSBUF 49152   // per K-tile buffer: A 32768 B + B 16384 B
#define BOFFS 32768    // B region offset within a buffer

typedef __attribute__((ext_vector_type(8))) short short8;
typedef __attribute__((ext_vector_type(4))) float floatx4;

__device__ __forceinline__ unsigned short f2bf(float f) {
  union { float f; uint32_t u; } v;
  v.f = f;
  return (unsigned short)((v.u + 0x7FFFu + ((v.u >> 16) & 1u)) >> 16);  // RNE
}

// pack 4 fp32 -> 4 bf16 (RNE) using HW packed cvt
__device__ __forceinline__ ushort4 cvt4(float4 v) {
  __hip_bfloat162 p0 = __float22bfloat162_rn(make_float2(v.x, v.y));
  __hip_bfloat162 p1 = __float22bfloat162_rn(make_float2(v.z, v.w));
  union { __hip_bfloat162 h[2]; ushort4 s; } u;
  u.h[0] = p0; u.h[1] = p1;
  return u.s;
}

// ---------------------------------------------------------------------------
// classify tokens (blocks 0..63) + convert weights to bf16 (blocks 64..).
// ---------------------------------------------------------------------------
__global__ __launch_bounds__(256) void classify_cvt_kernel(
    const int* __restrict__ idx, int* __restrict__ cnt,
    int* __restrict__ bucket, int* __restrict__ blocal, int N,
    const float* __restrict__ w0, const float* __restrict__ w1,
    const float* __restrict__ w2, unsigned short* __restrict__ wb0,
    unsigned short* __restrict__ wb1, unsigned short* __restrict__ wb2) {
  if (blockIdx.x < 64) {
    int n = blockIdx.x * 256 + threadIdx.x;
    int lane = threadIdx.x & 63;
    int c = -1, v = 0;
    if (n < N) {
      v = idx[n];
      c = (v < 20000) ? 0 : ((v < 40000) ? 1 : 2);
    }
#pragma unroll
    for (int k = 0; k < 3; ++k) {
      unsigned long long m = __ballot(c == k);
      if (c == k) {
        int leader = __ffsll((unsigned long long)m) - 1;
        int base = 0;
        if (lane == leader) base = atomicAdd(&cnt[k], (int)__popcll(m));
        base = __shfl(base, leader);
        int rank = (int)__popcll(m & ((1ull << (unsigned)lane) - 1ull));
        int lo = (k == 0) ? 0 : (k == 1) ? 20000 : 40000;
        bucket[k * NMAX + base + rank] = n;
        blocal[k * NMAX + base + rank] = v - lo;
      }
    }
  } else {
    int i = (blockIdx.x - 64) * 256 + threadIdx.x;
    if (i >= 344064) return;
    const float4* src;
    ushort4* dst;
    if (i < 262144) {            // w0: 1024x1024
      src = (const float4*)w0 + i;
      dst = (ushort4*)wb0 + i;
    } else if (i < 327680) {     // w1: 1024x256
      src = (const float4*)w1 + (i - 262144);
      dst = (ushort4*)wb1 + (i - 262144);
    } else {                     // w2: 1024x64
      src = (const float4*)w2 + (i - 327680);
      dst = (ushort4*)wb2 + (i - 327680);
    }
    float4 v = *src;
    ushort4 o;
    o.x = f2bf(v.x); o.y = f2bf(v.y); o.z = f2bf(v.z); o.w = f2bf(v.w);
    *dst = o;
  }
}

// ---------------------------------------------------------------------------
// Gather bucketed embedding rows -> packed bf16 A matrices.
//   Abf layout: [cnt0 x 1024][cnt1 x 256][cnt2 x 64] (+256-row slack)
// Per-thread: 4x float4 at lane-contiguous offsets (every load instr is a
// wave-contiguous 1KB segment; every store a wave-contiguous 512B segment).
// ---------------------------------------------------------------------------
__global__ __launch_bounds__(256) void gather_kernel(
    const float* __restrict__ emb0, const float* __restrict__ emb1,
    const float* __restrict__ emb2, const int* __restrict__ cnt,
    const int* __restrict__ blocal, unsigned short* __restrict__ Abf) {
  const int b = blockIdx.x;
  const int c0 = cnt[0], c1 = cnt[1], c2 = cnt[2];
  const float* emb;
  const int* bl;
  int H, count, baseRow, lg;
  size_t off;
  if (b < 4096) {
    emb = emb0; bl = blocal; H = 1024; count = c0; off = 0;
    baseRow = b * 4; lg = 6;
  } else if (b < 5120) {
    emb = emb1; bl = blocal + NMAX; H = 256; count = c1;
    off = (size_t)c0 * 1024; baseRow = (b - 4096) * 16; lg = 4;
  } else {
    emb = emb2; bl = blocal + 2 * NMAX; H = 64; count = c2;
    off = (size_t)c0 * 1024 + (size_t)c1 * 256; baseRow = (b - 5120) * 64; lg = 2;
  }
  const int tid = threadIdx.x;
  const int r = baseRow + (tid >> lg);
  if (r >= count) return;
  const int tpr = 1 << lg;           // threads per row (H/16)
  const int e = (tid & (tpr - 1)) * 4;  // first float4, element offset
  const int stride = tpr * 4;        // elements between chunks
  const float* src = emb + (size_t)bl[r] * H + e;
  unsigned short* d = Abf + off + (size_t)r * H + e;
#pragma unroll
  for (int j = 0; j < 4; ++j) {
    float4 v = *(const float4*)(src + j * stride);
    *(ushort4*)(d + j * stride) = cvt4(v);
  }
}

// ---------------------------------------------------------------------------
// Pipelined bf16 MFMA GEMM: BM=256 x BN=128, BK=64, 8 waves (4Mx2N).
// Triple-buffered LDS (3 x 48KB), counted vmcnt (never drains to 0 in the
// steady state), raw s_barrier, setprio around the MFMA cluster, XOR
// bank-swizzle both-sides. Fragments loaded ONCE per K-tile (16 ds_read_b128
// feeding 32 MFMA) -- half the LDS traffic of the quadrant-phase version.
// Bijective XCD swizzle so co-resident blocks on one XCD share the A panel
// in their XCD L2.
// ---------------------------------------------------------------------------
template <int H>
__device__ __forceinline__ void gemm_body(
    const unsigned short* __restrict__ A, const unsigned short* __restrict__ B,
    int count, const int* __restrict__ bucket, float* __restrict__ out,
    char* lds, int* rowTok) {
  // --- bijective XCD swizzle over the 2D (x,y) grid (nwg = 512, %8 == 0) --
  const int nwg = gridDim.x * gridDim.y;
  const int orig = blockIdx.y * gridDim.x + blockIdx.x;
  const int q = nwg >> 3;
  const int wg = (orig & 7) * q + (orig >> 3);
  const int bx = wg % gridDim.x;
  const int by = wg / gridDim.x;

  const int m0 = by * BM;
  if (m0 >= count) return;
  const int n0 = bx * BN;
  constexpr int NT = H / 64;

  const int tid = threadIdx.x;
  const int wave = tid >> 6;
  const int lane = tid & 63;
  const int quad = lane >> 4;
  const int l16 = lane & 15;
  const int wm = wave & 3;   // 4 m-waves: rows [wm*64, wm*64+64)
  const int wn = wave >> 2;  // 2 n-waves: cols [wn*64, wn*64+64)

  if (tid < BM) {
    int m = m0 + tid;
    rowTok[tid] = (m < count) ? bucket[m] : -1;
  }

  // --- staging: per-thread logical slot after the involution -------------
  const int dl = wave * 1024 + lane * 16;
  const int lswz = dl ^ (((dl >> 7) & 3) << 4);
  const int rW = lswz >> 6;
  const int ckW = (lswz >> 4) & 3;
  const char* Abyte = (const char*)A;
  const char* Bbyte = (const char*)B;
  const size_t aOff0 = ((size_t)(m0 + rW) * H) * 2 + ckW * 16;
  const size_t aOff1 = ((size_t)(m0 + 128 + rW) * H) * 2 + ckW * 16;
  const size_t bOff = ((size_t)(n0 + rW) * H) * 2 + ckW * 16;

  // stage one K-tile (6 x global_load_lds per thread) into buffer `buf`
  auto stage = [&](int kt, char* buf) {
    const int kb = kt * 128;  // 64 k-elems * 2B per K-tile
#pragma unroll
    for (int s = 0; s < 2; ++s) {
      __builtin_amdgcn_global_load_lds(
          (const __attribute__((address_space(1))) void*)(Abyte + aOff0 + kb + s * 64),
          (__attribute__((address_space(3))) void*)(buf + s * 16384 + wave * 1024),
          16, 0, 0);
      __builtin_amdgcn_global_load_lds(
          (const __attribute__((address_space(1))) void*)(Abyte + aOff1 + kb + s * 64),
          (__attribute__((address_space(3))) void*)(buf + s * 16384 + 8192 + wave * 1024),
          16, 0, 0);
      __builtin_amdgcn_global_load_lds(
          (const __attribute__((address_space(1))) void*)(Bbyte + bOff + kb + s * 64),
          (__attribute__((address_space(3))) void*)(buf + BOFFS + s * 8192 + wave * 1024),
          16, 0, 0);
    }
  };

  // --- fragment read offsets (K-invariant, swizzled) ---------------------
  int offA[2][4], offB[2][4];
#pragma unroll
  for (int s = 0; s < 2; ++s) {
#pragma unroll
    for (int i = 0; i < 4; ++i) {
      int ba = (wm * 64 + i * 16 + l16) * 64 + quad * 16;
      offA[s][i] = s * 16384 + (ba ^ (((ba >> 7) & 3) << 4));
      int bb = (wn * 64 + i * 16 + l16) * 64 + quad * 16;
      offB[s][i] = BOFFS + s * 8192 + (bb ^ (((bb >> 7) & 3) << 4));
    }
  }

  // --- prologue: fill the 3-deep pipeline --------------------------------
  if (NT >= 1) stage(0, lds);
  if (NT >= 2) stage(1, lds + LDSBUF);
  if (NT >= 3) stage(2, lds + 2 * LDSBUF);

  floatx4 acc[4][4];
#pragma unroll
  for (int i = 0; i < 4; ++i)
#pragma unroll
    for (int j = 0; j < 4; ++j) acc[i][j] = (floatx4){0.f, 0.f, 0.f, 0.f};

#pragma unroll
  for (int kt = 0; kt < NT; ++kt) {
    // counted wait: K-tile kt's 6 loads landed; up to 12 stay in flight
    const int rem = NT - 1 - kt;
    if (rem >= 2)
      asm volatile("s_waitcnt vmcnt(12)" ::: "memory");
    else if (rem == 1)
      asm volatile("s_waitcnt vmcnt(6)" ::: "memory");
    else
      asm volatile("s_waitcnt vmcnt(0)" ::: "memory");
    asm volatile("s_barrier" ::: "memory");  // all waves' slices landed

    const char* buf = lds + (kt % 3) * LDSBUF;
    // load ALL fragments once (16 ds_read_b128), then 32 MFMA
    short8 a[2][4], b[2][4];
#pragma unroll
    for (int s = 0; s < 2; ++s)
#pragma unroll
      for (int i = 0; i < 4; ++i) {
        a[s][i] = *(const short8*)(buf + offA[s][i]);
        b[s][i] = *(const short8*)(buf + offB[s][i]);
      }
    __builtin_amdgcn_s_setprio(1);
#pragma unroll
    for (int s = 0; s < 2; ++s)
#pragma unroll
      for (int i = 0; i < 4; ++i)
#pragma unroll
        for (int j = 0; j < 4; ++j)
          acc[i][j] = __builtin_amdgcn_mfma_f32_16x16x32_bf16(
              a[s][i], b[s][j], acc[i][j], 0, 0, 0);
    __builtin_amdgcn_s_setprio(0);
    asm volatile("s_barrier" ::: "memory");  // all reads of buf done
    if (kt + 3 < NT) stage(kt + 3, lds + (kt % 3) * LDSBUF);
  }

  // --- epilogue: scatter rows (C/D: col=lane&15, row=quad*4+reg) ---------
  const int colBase = n0 + wn * 64 + l16;
#pragma unroll
  for (int mi = 0; mi < 4; ++mi) {
#pragma unroll
    for (int r = 0; r < 4; ++r) {
      int tok = rowTok[wm * 64 + mi * 16 + quad * 4 + r];
      if (tok >= 0) {
        float* o = out + (size_t)tok * DOUT + colBase;
#pragma unroll
        for (int ni = 0; ni < 4; ++ni) o[ni * 16] = acc[mi][ni][r];
      }
    }
  }
}

__global__ __launch_bounds__(512, 2) void gemm_pipe(
    const unsigned short* __restrict__ Abf,
    const unsigned short* __restrict__ wb0,
    const unsigned short* __restrict__ wb1,
    const unsigned short* __restrict__ wb2, const int* __restrict__ cnt,
    const int* __restrict__ bucket, float* __restrict__ out) {
  __shared__ __align__(16) char lds[3 * LDSBUF + BM * 4];
  int* rowTok = (int*)(lds + 3 * LDSBUF);

  const int z = blockIdx.z;
  const int c0 = cnt[0];
  const int c1 = cnt[1];
  if (z == 0)
    gemm_body<1024>(Abf, wb0, c0, bucket, out, lds, rowTok);
  else if (z == 1)
    gemm_body<256>(Abf + (size_t)c0 * 1024, wb1, c1, bucket + NMAX, out, lds,
                   rowTok);
  else
    gemm_body<64>(Abf + (size_t)c0 * 1024 + (size_t)c1 * 256, wb2, cnt[2],
                  bucket + 2 * NMAX, out, lds, rowTok);
}

extern "C" void kernel_launch(void* const* d_in, const int* in_sizes, int n_in,
                              void* d_out, int out_size, void* d_ws, size_t ws_size,
                              hipStream_t stream) {
  const int* idx = (const int*)d_in[0];
  const float* emb0 = (const float*)d_in[1];
  const float* w0 = (const float*)d_in[2];
  const float* emb1 = (const float*)d_in[3];
  const float* w1 = (const float*)d_in[4];
  const float* emb2 = (const float*)d_in[5];
  const float* w2 = (const float*)d_in[6];
  float* out = (float*)d_out;
  const int N = in_sizes[0];  // 16384

  // ---- workspace layout ----
  char* ws = (char*)d_ws;
  int* cnt = (int*)ws;                              // 64 B
  int* bucket = (int*)(ws + 1024);                  // 3*NMAX ints
  int* blocal = bucket + 3 * NMAX;                  // 3*NMAX ints
  size_t off = 1024 + (size_t)6 * NMAX * 4;
  off = (off + 255) & ~(size_t)255;
  unsigned short* wb0 = (unsigned short*)(ws + off); off += (size_t)DOUT * 1024 * 2;
  unsigned short* wb1 = (unsigned short*)(ws + off); off += (size_t)DOUT * 256 * 2;
  unsigned short* wb2 = (unsigned short*)(ws + off); off += (size_t)DOUT * 64 * 2;
  off = (off + 255) & ~(size_t)255;
  unsigned short* Abf = (unsigned short*)(ws + off);
  off += (size_t)(NMAX + 256) * 1024 * 2;  // packed A + BM-row tile slack

  hipMemsetAsync(cnt, 0, 16 * sizeof(int), stream);

  // classify (64 blocks) + weight cvt (1344 blocks)
  classify_cvt_kernel<<<64 + 1344, 256, 0, stream>>>(
      idx, cnt, bucket, blocal, N, w0, w1, w2, wb0, wb1, wb2);

  // gather bucketed emb rows -> packed bf16 A
  gather_kernel<<<5376, 256, 0, stream>>>(emb0, emb1, emb2, cnt, blocal, Abf);

  // pipelined GEMM per cluster: z = cluster
  dim3 grid(DOUT / BN, NMAX / BM, 3);
  gemm_pipe<<<grid, 512, 0, stream>>>(Abf, wb0, wb1, wb2, cnt, bucket, out);
}

// Round 4
// 202.231 us; speedup vs baseline: 1.1559x; 1.1559x over previous
//
#include <hip/hip_runtime.h>
#include <hip/hip_bf16.h>
#include <stdint.h>

#define DOUT 1024
#define NMAX 16384

#define BM 256
#define BN 128
#define LDSBUF 49152   // per K-tile buffer: A 32768 B + B 16384 B
#define BOFFS 32768    // B region offset within a buffer

typedef __attribute__((ext_vector_type(8))) short short8;
typedef __attribute__((ext_vector_type(4))) float floatx4;

__device__ __forceinline__ unsigned short f2bf(float f) {
  union { float f; uint32_t u; } v;
  v.f = f;
  return (unsigned short)((v.u + 0x7FFFu + ((v.u >> 16) & 1u)) >> 16);  // RNE
}

// pack 4 fp32 -> 4 bf16 (RNE) using HW packed cvt
__device__ __forceinline__ ushort4 cvt4(float4 v) {
  __hip_bfloat162 p0 = __float22bfloat162_rn(make_float2(v.x, v.y));
  __hip_bfloat162 p1 = __float22bfloat162_rn(make_float2(v.z, v.w));
  union { __hip_bfloat162 h[2]; ushort4 s; } u;
  u.h[0] = p0; u.h[1] = p1;
  return u.s;
}

// ---------------------------------------------------------------------------
// classify tokens (blocks 0..63) + convert weights to bf16 (blocks 64..).
// ---------------------------------------------------------------------------
__global__ __launch_bounds__(256) void classify_cvt_kernel(
    const int* __restrict__ idx, int* __restrict__ cnt,
    int* __restrict__ bucket, int* __restrict__ blocal, int N,
    const float* __restrict__ w0, const float* __restrict__ w1,
    const float* __restrict__ w2, unsigned short* __restrict__ wb0,
    unsigned short* __restrict__ wb1, unsigned short* __restrict__ wb2) {
  if (blockIdx.x < 64) {
    int n = blockIdx.x * 256 + threadIdx.x;
    int lane = threadIdx.x & 63;
    int c = -1, v = 0;
    if (n < N) {
      v = idx[n];
      c = (v < 20000) ? 0 : ((v < 40000) ? 1 : 2);
    }
#pragma unroll
    for (int k = 0; k < 3; ++k) {
      unsigned long long m = __ballot(c == k);
      if (c == k) {
        int leader = __ffsll((unsigned long long)m) - 1;
        int base = 0;
        if (lane == leader) base = atomicAdd(&cnt[k], (int)__popcll(m));
        base = __shfl(base, leader);
        int rank = (int)__popcll(m & ((1ull << (unsigned)lane) - 1ull));
        int lo = (k == 0) ? 0 : (k == 1) ? 20000 : 40000;
        bucket[k * NMAX + base + rank] = n;
        blocal[k * NMAX + base + rank] = v - lo;
      }
    }
  } else {
    int i = (blockIdx.x - 64) * 256 + threadIdx.x;
    if (i >= 344064) return;
    const float4* src;
    ushort4* dst;
    if (i < 262144) {            // w0: 1024x1024
      src = (const float4*)w0 + i;
      dst = (ushort4*)wb0 + i;
    } else if (i < 327680) {     // w1: 1024x256
      src = (const float4*)w1 + (i - 262144);
      dst = (ushort4*)wb1 + (i - 262144);
    } else {                     // w2: 1024x64
      src = (const float4*)w2 + (i - 327680);
      dst = (ushort4*)wb2 + (i - 327680);
    }
    float4 v = *src;
    ushort4 o;
    o.x = f2bf(v.x); o.y = f2bf(v.y); o.z = f2bf(v.z); o.w = f2bf(v.w);
    *dst = o;
  }
}

// ---------------------------------------------------------------------------
// Gather bucketed embedding rows -> packed bf16 A matrices.
//   Abf layout: [cnt0 x 1024][cnt1 x 256][cnt2 x 64] (+256-row slack)
// Per-thread: 4x float4 at lane-contiguous offsets (every load instr is a
// wave-contiguous 1KB segment; every store a wave-contiguous 512B segment).
// ---------------------------------------------------------------------------
__global__ __launch_bounds__(256) void gather_kernel(
    const float* __restrict__ emb0, const float* __restrict__ emb1,
    const float* __restrict__ emb2, const int* __restrict__ cnt,
    const int* __restrict__ blocal, unsigned short* __restrict__ Abf) {
  const int b = blockIdx.x;
  const int c0 = cnt[0], c1 = cnt[1], c2 = cnt[2];
  const float* emb;
  const int* bl;
  int H, count, baseRow, lg;
  size_t off;
  if (b < 4096) {
    emb = emb0; bl = blocal; H = 1024; count = c0; off = 0;
    baseRow = b * 4; lg = 6;
  } else if (b < 5120) {
    emb = emb1; bl = blocal + NMAX; H = 256; count = c1;
    off = (size_t)c0 * 1024; baseRow = (b - 4096) * 16; lg = 4;
  } else {
    emb = emb2; bl = blocal + 2 * NMAX; H = 64; count = c2;
    off = (size_t)c0 * 1024 + (size_t)c1 * 256; baseRow = (b - 5120) * 64; lg = 2;
  }
  const int tid = threadIdx.x;
  const int r = baseRow + (tid >> lg);
  if (r >= count) return;
  const int tpr = 1 << lg;           // threads per row (H/16)
  const int e = (tid & (tpr - 1)) * 4;  // first float4, element offset
  const int stride = tpr * 4;        // elements between chunks
  const float* src = emb + (size_t)bl[r] * H + e;
  unsigned short* d = Abf + off + (size_t)r * H + e;
#pragma unroll
  for (int j = 0; j < 4; ++j) {
    float4 v = *(const float4*)(src + j * stride);
    *(ushort4*)(d + j * stride) = cvt4(v);
  }
}

// ---------------------------------------------------------------------------
// Pipelined bf16 MFMA GEMM: BM=256 x BN=128, BK=64, 8 waves (4Mx2N).
// Triple-buffered LDS (3 x 48KB), counted vmcnt (never drains to 0 in the
// steady state), raw s_barrier, setprio around the MFMA cluster, XOR
// bank-swizzle both-sides (0 conflicts measured). Fragments loaded ONCE per
// K-tile (16 ds_read_b128 feeding 32 MFMA).
// XCD mapping: by ≡ xcd (mod 8) — balanced over the ACTIVE tile prefix
// (round-3 lesson: chunked by-ranges starved 5/8 XCDs when count << NMAX)
// while keeping each XCD's A panels (≤2MB) + B (2MB) resident in its L2.
// ---------------------------------------------------------------------------
template <int H>
__device__ __forceinline__ void gemm_body(
    const unsigned short* __restrict__ A, const unsigned short* __restrict__ B,
    int count, const int* __restrict__ bucket, float* __restrict__ out,
    char* lds, int* rowTok) {
  // grid is (x=8, y=64); orig%8 ~ XCD. Give XCD k rows by ≡ k (mod 8).
  const int orig = blockIdx.y * gridDim.x + blockIdx.x;
  const int by = (orig & 7) + 8 * (orig >> 6);
  const int bx = (orig >> 3) & 7;

  const int m0 = by * BM;
  if (m0 >= count) return;
  const int n0 = bx * BN;
  constexpr int NT = H / 64;

  const int tid = threadIdx.x;
  const int wave = tid >> 6;
  const int lane = tid & 63;
  const int quad = lane >> 4;
  const int l16 = lane & 15;
  const int wm = wave & 3;   // 4 m-waves: rows [wm*64, wm*64+64)
  const int wn = wave >> 2;  // 2 n-waves: cols [wn*64, wn*64+64)

  if (tid < BM) {
    int m = m0 + tid;
    rowTok[tid] = (m < count) ? bucket[m] : -1;
  }

  // --- staging: per-thread logical slot after the involution -------------
  const int dl = wave * 1024 + lane * 16;
  const int lswz = dl ^ (((dl >> 7) & 3) << 4);
  const int rW = lswz >> 6;
  const int ckW = (lswz >> 4) & 3;
  const char* Abyte = (const char*)A;
  const char* Bbyte = (const char*)B;
  const size_t aOff0 = ((size_t)(m0 + rW) * H) * 2 + ckW * 16;
  const size_t aOff1 = ((size_t)(m0 + 128 + rW) * H) * 2 + ckW * 16;
  const size_t bOff = ((size_t)(n0 + rW) * H) * 2 + ckW * 16;

  // stage one K-tile (6 x global_load_lds per thread) into buffer `buf`
  auto stage = [&](int kt, char* buf) {
    const int kb = kt * 128;  // 64 k-elems * 2B per K-tile
#pragma unroll
    for (int s = 0; s < 2; ++s) {
      __builtin_amdgcn_global_load_lds(
          (const __attribute__((address_space(1))) void*)(Abyte + aOff0 + kb + s * 64),
          (__attribute__((address_space(3))) void*)(buf + s * 16384 + wave * 1024),
          16, 0, 0);
      __builtin_amdgcn_global_load_lds(
          (const __attribute__((address_space(1))) void*)(Abyte + aOff1 + kb + s * 64),
          (__attribute__((address_space(3))) void*)(buf + s * 16384 + 8192 + wave * 1024),
          16, 0, 0);
      __builtin_amdgcn_global_load_lds(
          (const __attribute__((address_space(1))) void*)(Bbyte + bOff + kb + s * 64),
          (__attribute__((address_space(3))) void*)(buf + BOFFS + s * 8192 + wave * 1024),
          16, 0, 0);
    }
  };

  // --- fragment read offsets (K-invariant, swizzled) ---------------------
  int offA[2][4], offB[2][4];
#pragma unroll
  for (int s = 0; s < 2; ++s) {
#pragma unroll
    for (int i = 0; i < 4; ++i) {
      int ba = (wm * 64 + i * 16 + l16) * 64 + quad * 16;
      offA[s][i] = s * 16384 + (ba ^ (((ba >> 7) & 3) << 4));
      int bb = (wn * 64 + i * 16 + l16) * 64 + quad * 16;
      offB[s][i] = BOFFS + s * 8192 + (bb ^ (((bb >> 7) & 3) << 4));
    }
  }

  // --- prologue: fill the 3-deep pipeline --------------------------------
  if (NT >= 1) stage(0, lds);
  if (NT >= 2) stage(1, lds + LDSBUF);
  if (NT >= 3) stage(2, lds + 2 * LDSBUF);

  floatx4 acc[4][4];
#pragma unroll
  for (int i = 0; i < 4; ++i)
#pragma unroll
    for (int j = 0; j < 4; ++j) acc[i][j] = (floatx4){0.f, 0.f, 0.f, 0.f};

#pragma unroll
  for (int kt = 0; kt < NT; ++kt) {
    // counted wait: K-tile kt's 6 loads landed; up to 12 stay in flight
    const int rem = NT - 1 - kt;
    if (rem >= 2)
      asm volatile("s_waitcnt vmcnt(12)" ::: "memory");
    else if (rem == 1)
      asm volatile("s_waitcnt vmcnt(6)" ::: "memory");
    else
      asm volatile("s_waitcnt vmcnt(0)" ::: "memory");
    asm volatile("s_barrier" ::: "memory");  // all waves' slices landed

    const char* buf = lds + (kt % 3) * LDSBUF;
    // load ALL fragments once (16 ds_read_b128), then 32 MFMA
    short8 a[2][4], b[2][4];
#pragma unroll
    for (int s = 0; s < 2; ++s)
#pragma unroll
      for (int i = 0; i < 4; ++i) {
        a[s][i] = *(const short8*)(buf + offA[s][i]);
        b[s][i] = *(const short8*)(buf + offB[s][i]);
      }
    __builtin_amdgcn_s_setprio(1);
#pragma unroll
    for (int s = 0; s < 2; ++s)
#pragma unroll
      for (int i = 0; i < 4; ++i)
#pragma unroll
        for (int j = 0; j < 4; ++j)
          acc[i][j] = __builtin_amdgcn_mfma_f32_16x16x32_bf16(
              a[s][i], b[s][j], acc[i][j], 0, 0, 0);
    __builtin_amdgcn_s_setprio(0);
    asm volatile("s_barrier" ::: "memory");  // all reads of buf done
    if (kt + 3 < NT) stage(kt + 3, lds + (kt % 3) * LDSBUF);
  }

  // --- epilogue: scatter rows (C/D: col=lane&15, row=quad*4+reg) ---------
  const int colBase = n0 + wn * 64 + l16;
#pragma unroll
  for (int mi = 0; mi < 4; ++mi) {
#pragma unroll
    for (int r = 0; r < 4; ++r) {
      int tok = rowTok[wm * 64 + mi * 16 + quad * 4 + r];
      if (tok >= 0) {
        float* o = out + (size_t)tok * DOUT + colBase;
#pragma unroll
        for (int ni = 0; ni < 4; ++ni) o[ni * 16] = acc[mi][ni][r];
      }
    }
  }
}

__global__ __launch_bounds__(512, 2) void gemm_pipe(
    const unsigned short* __restrict__ Abf,
    const unsigned short* __restrict__ wb0,
    const unsigned short* __restrict__ wb1,
    const unsigned short* __restrict__ wb2, const int* __restrict__ cnt,
    const int* __restrict__ bucket, float* __restrict__ out) {
  __shared__ __align__(16) char lds[3 * LDSBUF + BM * 4];
  int* rowTok = (int*)(lds + 3 * LDSBUF);

  const int z = blockIdx.z;
  const int c0 = cnt[0];
  const int c1 = cnt[1];
  if (z == 0)
    gemm_body<1024>(Abf, wb0, c0, bucket, out, lds, rowTok);
  else if (z == 1)
    gemm_body<256>(Abf + (size_t)c0 * 1024, wb1, c1, bucket + NMAX, out, lds,
                   rowTok);
  else
    gemm_body<64>(Abf + (size_t)c0 * 1024 + (size_t)c1 * 256, wb2, cnt[2],
                  bucket + 2 * NMAX, out, lds, rowTok);
}

extern "C" void kernel_launch(void* const* d_in, const int* in_sizes, int n_in,
                              void* d_out, int out_size, void* d_ws, size_t ws_size,
                              hipStream_t stream) {
  const int* idx = (const int*)d_in[0];
  const float* emb0 = (const float*)d_in[1];
  const float* w0 = (const float*)d_in[2];
  const float* emb1 = (const float*)d_in[3];
  const float* w1 = (const float*)d_in[4];
  const float* emb2 = (const float*)d_in[5];
  const float* w2 = (const float*)d_in[6];
  float* out = (float*)d_out;
  const int N = in_sizes[0];  // 16384

  // ---- workspace layout ----
  char* ws = (char*)d_ws;
  int* cnt = (int*)ws;                              // 64 B
  int* bucket = (int*)(ws + 1024);                  // 3*NMAX ints
  int* blocal = bucket + 3 * NMAX;                  // 3*NMAX ints
  size_t off = 1024 + (size_t)6 * NMAX * 4;
  off = (off + 255) & ~(size_t)255;
  unsigned short* wb0 = (unsigned short*)(ws + off); off += (size_t)DOUT * 1024 * 2;
  unsigned short* wb1 = (unsigned short*)(ws + off); off += (size_t)DOUT * 256 * 2;
  unsigned short* wb2 = (unsigned short*)(ws + off); off += (size_t)DOUT * 64 * 2;
  off = (off + 255) & ~(size_t)255;
  unsigned short* Abf = (unsigned short*)(ws + off);
  off += (size_t)(NMAX + 256) * 1024 * 2;  // packed A + BM-row tile slack

  hipMemsetAsync(cnt, 0, 16 * sizeof(int), stream);

  // classify (64 blocks) + weight cvt (1344 blocks)
  classify_cvt_kernel<<<64 + 1344, 256, 0, stream>>>(
      idx, cnt, bucket, blocal, N, w0, w1, w2, wb0, wb1, wb2);

  // gather bucketed emb rows -> packed bf16 A
  gather_kernel<<<5376, 256, 0, stream>>>(emb0, emb1, emb2, cnt, blocal, Abf);

  // pipelined GEMM per cluster: z = cluster
  dim3 grid(DOUT / BN, NMAX / BM, 3);
  gemm_pipe<<<grid, 512, 0, stream>>>(Abf, wb0, wb1, wb2, cnt, bucket, out);
}

// Round 5
// 198.521 us; speedup vs baseline: 1.1775x; 1.0187x over previous
//
#include <hip/hip_runtime.h>
#include <hip/hip_bf16.h>
#include <stdint.h>

#define DOUT 1024
#define NMAX 16384

#define BM 256
#define BN 128
#define LDSBUF 49152   // per K-tile buffer: A 32768 B + B 16384 B
#define BOFFS 32768    // B region offset within a buffer

typedef __attribute__((ext_vector_type(8))) short short8;
typedef __attribute__((ext_vector_type(4))) float floatx4;

__device__ __forceinline__ unsigned short f2bf(float f) {
  union { float f; uint32_t u; } v;
  v.f = f;
  return (unsigned short)((v.u + 0x7FFFu + ((v.u >> 16) & 1u)) >> 16);  // RNE
}

// pack 4 fp32 -> 4 bf16 (RNE) using HW packed cvt
__device__ __forceinline__ ushort4 cvt4(float4 v) {
  __hip_bfloat162 p0 = __float22bfloat162_rn(make_float2(v.x, v.y));
  __hip_bfloat162 p1 = __float22bfloat162_rn(make_float2(v.z, v.w));
  union { __hip_bfloat162 h[2]; ushort4 s; } u;
  u.h[0] = p0; u.h[1] = p1;
  return u.s;
}

// ---------------------------------------------------------------------------
// classify tokens (blocks 0..63) + convert weights to bf16 (blocks 64..).
// ---------------------------------------------------------------------------
__global__ __launch_bounds__(256) void classify_cvt_kernel(
    const int* __restrict__ idx, int* __restrict__ cnt,
    int* __restrict__ bucket, int* __restrict__ blocal, int N,
    const float* __restrict__ w0, const float* __restrict__ w1,
    const float* __restrict__ w2, unsigned short* __restrict__ wb0,
    unsigned short* __restrict__ wb1, unsigned short* __restrict__ wb2) {
  if (blockIdx.x < 64) {
    int n = blockIdx.x * 256 + threadIdx.x;
    int lane = threadIdx.x & 63;
    int c = -1, v = 0;
    if (n < N) {
      v = idx[n];
      c = (v < 20000) ? 0 : ((v < 40000) ? 1 : 2);
    }
#pragma unroll
    for (int k = 0; k < 3; ++k) {
      unsigned long long m = __ballot(c == k);
      if (c == k) {
        int leader = __ffsll((unsigned long long)m) - 1;
        int base = 0;
        if (lane == leader) base = atomicAdd(&cnt[k], (int)__popcll(m));
        base = __shfl(base, leader);
        int rank = (int)__popcll(m & ((1ull << (unsigned)lane) - 1ull));
        int lo = (k == 0) ? 0 : (k == 1) ? 20000 : 40000;
        bucket[k * NMAX + base + rank] = n;
        blocal[k * NMAX + base + rank] = v - lo;
      }
    }
  } else {
    int i = (blockIdx.x - 64) * 256 + threadIdx.x;
    if (i >= 344064) return;
    const float4* src;
    ushort4* dst;
    if (i < 262144) {            // w0: 1024x1024
      src = (const float4*)w0 + i;
      dst = (ushort4*)wb0 + i;
    } else if (i < 327680) {     // w1: 1024x256
      src = (const float4*)w1 + (i - 262144);
      dst = (ushort4*)wb1 + (i - 262144);
    } else {                     // w2: 1024x64
      src = (const float4*)w2 + (i - 327680);
      dst = (ushort4*)wb2 + (i - 327680);
    }
    float4 v = *src;
    ushort4 o;
    o.x = f2bf(v.x); o.y = f2bf(v.y); o.z = f2bf(v.z); o.w = f2bf(v.w);
    *dst = o;
  }
}

// ---------------------------------------------------------------------------
// Gather bucketed embedding rows -> packed bf16 A matrices.
//   Abf layout: [cnt0 x 1024][cnt1 x 256][cnt2 x 64] (+256-row slack)
// ---------------------------------------------------------------------------
__global__ __launch_bounds__(256) void gather_kernel(
    const float* __restrict__ emb0, const float* __restrict__ emb1,
    const float* __restrict__ emb2, const int* __restrict__ cnt,
    const int* __restrict__ blocal, unsigned short* __restrict__ Abf) {
  const int b = blockIdx.x;
  const int c0 = cnt[0], c1 = cnt[1], c2 = cnt[2];
  const float* emb;
  const int* bl;
  int H, count, baseRow, lg;
  size_t off;
  if (b < 4096) {
    emb = emb0; bl = blocal; H = 1024; count = c0; off = 0;
    baseRow = b * 4; lg = 6;
  } else if (b < 5120) {
    emb = emb1; bl = blocal + NMAX; H = 256; count = c1;
    off = (size_t)c0 * 1024; baseRow = (b - 4096) * 16; lg = 4;
  } else {
    emb = emb2; bl = blocal + 2 * NMAX; H = 64; count = c2;
    off = (size_t)c0 * 1024 + (size_t)c1 * 256; baseRow = (b - 5120) * 64; lg = 2;
  }
  const int tid = threadIdx.x;
  const int r = baseRow + (tid >> lg);
  if (r >= count) return;
  const int tpr = 1 << lg;              // threads per row (H/16)
  const int e = (tid & (tpr - 1)) * 4;  // first float4, element offset
  const int stride = tpr * 4;           // elements between chunks
  const float* src = emb + (size_t)bl[r] * H + e;
  unsigned short* d = Abf + off + (size_t)r * H + e;
#pragma unroll
  for (int j = 0; j < 4; ++j) {
    float4 v = *(const float4*)(src + j * stride);
    *(ushort4*)(d + j * stride) = cvt4(v);
  }
}

// ---------------------------------------------------------------------------
// One 256x128 output tile: triple-buffered pipeline, counted vmcnt, XOR
// bank-swizzle both-sides (0 conflicts measured r3), load-once fragments
// (16 ds_read_b128 -> 32 MFMA per K-tile), setprio around the MFMA cluster.
// ---------------------------------------------------------------------------
template <int H>
__device__ __forceinline__ void tile_compute(
    const unsigned short* __restrict__ A, const unsigned short* __restrict__ B,
    int count, const int* __restrict__ bucket, float* __restrict__ out,
    char* lds, int* rowTok, int by, int bx) {
  constexpr int NT = H / 64;
  const int m0 = by * BM;
  const int n0 = bx * BN;

  const int tid = threadIdx.x;
  const int wave = tid >> 6;
  const int lane = tid & 63;
  const int quad = lane >> 4;
  const int l16 = lane & 15;
  const int wm = wave & 3;   // 4 m-waves: rows [wm*64, wm*64+64)
  const int wn = wave >> 2;  // 2 n-waves: cols [wn*64, wn*64+64)

  if (tid < BM) {
    int m = m0 + tid;
    rowTok[tid] = (m < count) ? bucket[m] : -1;
  }

  // staging: per-thread logical slot after the involution
  const int dl = wave * 1024 + lane * 16;
  const int lswz = dl ^ (((dl >> 7) & 3) << 4);
  const int rW = lswz >> 6;
  const int ckW = (lswz >> 4) & 3;
  const char* Abyte = (const char*)A;
  const char* Bbyte = (const char*)B;
  const size_t aOff0 = ((size_t)(m0 + rW) * H) * 2 + ckW * 16;
  const size_t aOff1 = ((size_t)(m0 + 128 + rW) * H) * 2 + ckW * 16;
  const size_t bOff = ((size_t)(n0 + rW) * H) * 2 + ckW * 16;

  auto stage = [&](int kt, char* buf) {
    const int kb = kt * 128;  // 64 k-elems * 2B per K-tile
#pragma unroll
    for (int s = 0; s < 2; ++s) {
      __builtin_amdgcn_global_load_lds(
          (const __attribute__((address_space(1))) void*)(Abyte + aOff0 + kb + s * 64),
          (__attribute__((address_space(3))) void*)(buf + s * 16384 + wave * 1024),
          16, 0, 0);
      __builtin_amdgcn_global_load_lds(
          (const __attribute__((address_space(1))) void*)(Abyte + aOff1 + kb + s * 64),
          (__attribute__((address_space(3))) void*)(buf + s * 16384 + 8192 + wave * 1024),
          16, 0, 0);
      __builtin_amdgcn_global_load_lds(
          (const __attribute__((address_space(1))) void*)(Bbyte + bOff + kb + s * 64),
          (__attribute__((address_space(3))) void*)(buf + BOFFS + s * 8192 + wave * 1024),
          16, 0, 0);
    }
  };

  // fragment read offsets (K-invariant, swizzled)
  int offA[2][4], offB[2][4];
#pragma unroll
  for (int s = 0; s < 2; ++s) {
#pragma unroll
    for (int i = 0; i < 4; ++i) {
      int ba = (wm * 64 + i * 16 + l16) * 64 + quad * 16;
      offA[s][i] = s * 16384 + (ba ^ (((ba >> 7) & 3) << 4));
      int bb = (wn * 64 + i * 16 + l16) * 64 + quad * 16;
      offB[s][i] = BOFFS + s * 8192 + (bb ^ (((bb >> 7) & 3) << 4));
    }
  }

  // prologue: fill the 3-deep pipeline
  if (NT >= 1) stage(0, lds);
  if (NT >= 2) stage(1, lds + LDSBUF);
  if (NT >= 3) stage(2, lds + 2 * LDSBUF);

  floatx4 acc[4][4];
#pragma unroll
  for (int i = 0; i < 4; ++i)
#pragma unroll
    for (int j = 0; j < 4; ++j) acc[i][j] = (floatx4){0.f, 0.f, 0.f, 0.f};

#pragma unroll
  for (int kt = 0; kt < NT; ++kt) {
    const int rem = NT - 1 - kt;
    if (rem >= 2)
      asm volatile("s_waitcnt vmcnt(12)" ::: "memory");
    else if (rem == 1)
      asm volatile("s_waitcnt vmcnt(6)" ::: "memory");
    else
      asm volatile("s_waitcnt vmcnt(0)" ::: "memory");
    asm volatile("s_barrier" ::: "memory");  // all waves' slices landed

    const char* buf = lds + (kt % 3) * LDSBUF;
    short8 a[2][4], b[2][4];
#pragma unroll
    for (int s = 0; s < 2; ++s)
#pragma unroll
      for (int i = 0; i < 4; ++i) {
        a[s][i] = *(const short8*)(buf + offA[s][i]);
        b[s][i] = *(const short8*)(buf + offB[s][i]);
      }
    __builtin_amdgcn_s_setprio(1);
#pragma unroll
    for (int s = 0; s < 2; ++s)
#pragma unroll
      for (int i = 0; i < 4; ++i)
#pragma unroll
        for (int j = 0; j < 4; ++j)
          acc[i][j] = __builtin_amdgcn_mfma_f32_16x16x32_bf16(
              a[s][i], b[s][j], acc[i][j], 0, 0, 0);
    __builtin_amdgcn_s_setprio(0);
    asm volatile("s_barrier" ::: "memory");  // all reads of buf done
    if (kt + 3 < NT) stage(kt + 3, lds + (kt % 3) * LDSBUF);
  }

  // epilogue: scatter rows (C/D: col=lane&15, row=quad*4+reg)
  const int colBase = n0 + wn * 64 + l16;
#pragma unroll
  for (int mi = 0; mi < 4; ++mi) {
#pragma unroll
    for (int r = 0; r < 4; ++r) {
      int tok = rowTok[wm * 64 + mi * 16 + quad * 4 + r];
      if (tok >= 0) {
        float* o = out + (size_t)tok * DOUT + colBase;
#pragma unroll
        for (int ni = 0; ni < 4; ++ni) o[ni * 16] = acc[mi][ni][r];
      }
    }
  }
}

// ---------------------------------------------------------------------------
// Persistent work-stealing GEMM: 256 blocks (1/CU), global atomic tile queue
// ordered heavy-first (c0 tiles, then c1, then c2). Fixes the heterogeneous
// tile imbalance (round-4 lesson: static 2-round assignment left CUs ~73%
// idle; MfmaUtil 8% with all pipes quiet).
// ---------------------------------------------------------------------------
__global__ __launch_bounds__(512) void gemm_persist(
    const unsigned short* __restrict__ Abf,
    const unsigned short* __restrict__ wb0,
    const unsigned short* __restrict__ wb1,
    const unsigned short* __restrict__ wb2, const int* __restrict__ cnt,
    const int* __restrict__ bucket, float* __restrict__ out,
    int* __restrict__ tileCtr) {
  __shared__ __align__(16) char lds[3 * LDSBUF + BM * 4 + 16];
  int* rowTok = (int*)(lds + 3 * LDSBUF);
  int* curTile = (int*)(lds + 3 * LDSBUF + BM * 4);

  const int c0 = cnt[0], c1 = cnt[1], c2 = cnt[2];
  const int nt0 = (c0 + BM - 1) / BM;
  const int nt1 = (c1 + BM - 1) / BM;
  const int nt2 = (c2 + BM - 1) / BM;
  const int T0 = nt0 * 8, T1 = nt1 * 8, T2 = nt2 * 8;
  const int total = T0 + T1 + T2;
  const size_t o1 = (size_t)c0 * 1024;
  const size_t o2 = o1 + (size_t)c1 * 256;

  for (;;) {
    __syncthreads();  // prev tile fully done (epilogue + all LDS reads)
    if (threadIdx.x == 0) *curTile = atomicAdd(tileCtr, 1);
    __syncthreads();
    const int t = *curTile;
    if (t >= total) return;
    if (t < T0) {
      tile_compute<1024>(Abf, wb0, c0, bucket, out, lds, rowTok, t >> 3, t & 7);
    } else if (t < T0 + T1) {
      const int u = t - T0;
      tile_compute<256>(Abf + o1, wb1, c1, bucket + NMAX, out, lds, rowTok,
                        u >> 3, u & 7);
    } else {
      const int u = t - T0 - T1;
      tile_compute<64>(Abf + o2, wb2, c2, bucket + 2 * NMAX, out, lds, rowTok,
                       u >> 3, u & 7);
    }
  }
}

extern "C" void kernel_launch(void* const* d_in, const int* in_sizes, int n_in,
                              void* d_out, int out_size, void* d_ws, size_t ws_size,
                              hipStream_t stream) {
  const int* idx = (const int*)d_in[0];
  const float* emb0 = (const float*)d_in[1];
  const float* w0 = (const float*)d_in[2];
  const float* emb1 = (const float*)d_in[3];
  const float* w1 = (const float*)d_in[4];
  const float* emb2 = (const float*)d_in[5];
  const float* w2 = (const float*)d_in[6];
  float* out = (float*)d_out;
  const int N = in_sizes[0];  // 16384

  // ---- workspace layout ----
  char* ws = (char*)d_ws;
  int* cnt = (int*)ws;                              // 64 B (cnt[0..2], tileCtr at [8])
  int* bucket = (int*)(ws + 1024);                  // 3*NMAX ints
  int* blocal = bucket + 3 * NMAX;                  // 3*NMAX ints
  size_t off = 1024 + (size_t)6 * NMAX * 4;
  off = (off + 255) & ~(size_t)255;
  unsigned short* wb0 = (unsigned short*)(ws + off); off += (size_t)DOUT * 1024 * 2;
  unsigned short* wb1 = (unsigned short*)(ws + off); off += (size_t)DOUT * 256 * 2;
  unsigned short* wb2 = (unsigned short*)(ws + off); off += (size_t)DOUT * 64 * 2;
  off = (off + 255) & ~(size_t)255;
  unsigned short* Abf = (unsigned short*)(ws + off);
  off += (size_t)(NMAX + 256) * 1024 * 2;  // packed A + BM-row tile slack

  hipMemsetAsync(cnt, 0, 16 * sizeof(int), stream);  // zeroes cnt[0..15] incl. tileCtr

  // classify (64 blocks) + weight cvt (1344 blocks)
  classify_cvt_kernel<<<64 + 1344, 256, 0, stream>>>(
      idx, cnt, bucket, blocal, N, w0, w1, w2, wb0, wb1, wb2);

  // gather bucketed emb rows -> packed bf16 A
  gather_kernel<<<5376, 256, 0, stream>>>(emb0, emb1, emb2, cnt, blocal, Abf);

  // persistent work-stealing GEMM: 256 blocks, heavy-first tile queue
  gemm_persist<<<256, 512, 0, stream>>>(Abf, wb0, wb1, wb2, cnt, bucket, out,
                                        cnt + 8);
}